// Round 3
// baseline (192.800 us; speedup 1.0000x reference)
//
#include <hip/hip_runtime.h>

#define Tt 2048
#define Cc 512
#define Bb 4
#define BC (Bb * Cc)

typedef __attribute__((ext_vector_type(4))) float f32x4;
typedef __attribute__((ext_vector_type(8))) _Float16 f16x8;
typedef __attribute__((ext_vector_type(4))) _Float16 f16x4;
typedef __attribute__((ext_vector_type(2))) _Float16 f16x2;

// ---------------------------------------------------------------------------
// Kernel 0: W[k][n] (x4) -> Wt[z][n][k] fp16 (single plane).
// ---------------------------------------------------------------------------
__global__ __launch_bounds__(256) void wsetup(
    const float* __restrict__ Wq, const float* __restrict__ Wk,
    const float* __restrict__ Wv, const float* __restrict__ Wo,
    _Float16* __restrict__ Wt)
{
    const int z = blockIdx.y;
    const float* W = (z == 0) ? Wq : (z == 1) ? Wk : (z == 2) ? Wv : Wo;
    const int k0 = (blockIdx.x >> 3) * 64, n0 = (blockIdx.x & 7) * 64;
    const int tid = threadIdx.x;
    __shared__ float tile[64][65];

#pragma unroll
    for (int i = 0; i < 4; ++i) {
        const int idx = i * 256 + tid;
        const int kr = idx >> 4, c4 = idx & 15;
        float4 v = *(const float4*)&W[(size_t)(k0 + kr) * Cc + n0 + c4 * 4];
        tile[kr][c4 * 4 + 0] = v.x; tile[kr][c4 * 4 + 1] = v.y;
        tile[kr][c4 * 4 + 2] = v.z; tile[kr][c4 * 4 + 3] = v.w;
    }
    __syncthreads();
#pragma unroll
    for (int i = 0; i < 4; ++i) {
        const int idx = i * 256 + tid;
        const int nr = idx >> 4, k4 = idx & 15;
        f16x4 o;
        o[0] = (_Float16)tile[k4 * 4 + 0][nr];
        o[1] = (_Float16)tile[k4 * 4 + 1][nr];
        o[2] = (_Float16)tile[k4 * 4 + 2][nr];
        o[3] = (_Float16)tile[k4 * 4 + 3][nr];
        *(f16x4*)&Wt[((size_t)(z * 512 + n0 + nr)) * Cc + k0 + k4 * 4] = o;
    }
}

// ---------------------------------------------------------------------------
// Kernel 1: QKV GEMM, single-term fp16 MFMA. 128x128 tile, 4 waves, BK=32.
// Epilogue: fp16 store + per-(b,channel) column sum-of-squares (fp32 acc).
// ---------------------------------------------------------------------------
__global__ __launch_bounds__(256, 3) void qkv_mfma(
    const float* __restrict__ HS, const _Float16* __restrict__ Wt,
    _Float16* __restrict__ Qf, _Float16* __restrict__ Kf,
    _Float16* __restrict__ Vf, float* __restrict__ colsum)
{
    const int mt = blockIdx.x;              // 64
    const int nt = blockIdx.y;              // 4
    const int z  = blockIdx.z;              // 3
    _Float16* Out = (z == 0) ? Qf : (z == 1) ? Kf : Vf;

    const int tid = threadIdx.x;
    const int wave = tid >> 6, lane = tid & 63;
    const int quad = lane >> 4, lm = lane & 15;
    const int wm = (wave & 1) * 64, wn = (wave >> 1) * 64;

    __shared__ _Float16 sA[128 * 40];
    __shared__ _Float16 sB[128 * 40];

    f32x4 acc[4][4];
#pragma unroll
    for (int mf = 0; mf < 4; ++mf)
#pragma unroll
        for (int nf = 0; nf < 4; ++nf) acc[mf][nf] = (f32x4){0.f, 0.f, 0.f, 0.f};

    const int r2 = tid >> 1, kc = (tid & 1) * 16;
    const float* ga = HS + (size_t)(mt * 128 + r2) * Cc + kc;
    const _Float16* gb = Wt + ((size_t)(z * 512 + nt * 128 + r2)) * Cc + kc;

    for (int k0 = 0; k0 < Cc; k0 += 32) {
        __syncthreads();
        {
            float4 a0 = *(const float4*)&ga[k0];
            float4 a1 = *(const float4*)&ga[k0 + 4];
            float4 a2 = *(const float4*)&ga[k0 + 8];
            float4 a3 = *(const float4*)&ga[k0 + 12];
            f16x8 h0, h1;
            h0[0] = (_Float16)a0.x; h0[1] = (_Float16)a0.y;
            h0[2] = (_Float16)a0.z; h0[3] = (_Float16)a0.w;
            h0[4] = (_Float16)a1.x; h0[5] = (_Float16)a1.y;
            h0[6] = (_Float16)a1.z; h0[7] = (_Float16)a1.w;
            h1[0] = (_Float16)a2.x; h1[1] = (_Float16)a2.y;
            h1[2] = (_Float16)a2.z; h1[3] = (_Float16)a2.w;
            h1[4] = (_Float16)a3.x; h1[5] = (_Float16)a3.y;
            h1[6] = (_Float16)a3.z; h1[7] = (_Float16)a3.w;
            *(f16x8*)&sA[r2 * 40 + kc]     = h0;
            *(f16x8*)&sA[r2 * 40 + kc + 8] = h1;
            *(f16x8*)&sB[r2 * 40 + kc]     = *(const f16x8*)&gb[k0];
            *(f16x8*)&sB[r2 * 40 + kc + 8] = *(const f16x8*)&gb[k0 + 8];
        }
        __syncthreads();

        f16x8 ah[4], bh[4];
#pragma unroll
        for (int mf = 0; mf < 4; ++mf)
            ah[mf] = *(const f16x8*)&sA[(wm + mf * 16 + lm) * 40 + quad * 8];
#pragma unroll
        for (int nf = 0; nf < 4; ++nf)
            bh[nf] = *(const f16x8*)&sB[(wn + nf * 16 + lm) * 40 + quad * 8];
#pragma unroll
        for (int mf = 0; mf < 4; ++mf)
#pragma unroll
            for (int nf = 0; nf < 4; ++nf)
                acc[mf][nf] = __builtin_amdgcn_mfma_f32_16x16x32_f16(ah[mf], bh[nf], acc[mf][nf], 0, 0, 0);
    }

    const int bidx = mt >> 4;
#pragma unroll
    for (int nf = 0; nf < 4; ++nf) {
        float cs = 0.f;
#pragma unroll
        for (int mf = 0; mf < 4; ++mf)
#pragma unroll
            for (int r = 0; r < 4; ++r) {
                const float v = acc[mf][nf][r];
                const size_t idx =
                    (size_t)(mt * 128 + wm + mf * 16 + quad * 4 + r) * Cc +
                    nt * 128 + wn + nf * 16 + lm;
                Out[idx] = (_Float16)v;
                cs += v * v;
            }
        cs += __shfl_xor(cs, 16, 64);
        cs += __shfl_xor(cs, 32, 64);
        if (lane < 16)
            atomicAdd(&colsum[(size_t)z * BC + bidx * Cc + nt * 128 + wn + nf * 16 + lane], cs);
    }
}

// ---------------------------------------------------------------------------
// Kernel 2: colsum -> 1/sqrt(mean + eps)
// ---------------------------------------------------------------------------
__global__ void inv_norm_kernel(const float* __restrict__ colsum,
                                float* __restrict__ inv)
{
    const int i = blockIdx.x * blockDim.x + threadIdx.x;
    if (i < 3 * BC) inv[i] = rsqrtf(colsum[i] * (1.0f / Tt) + 1e-4f);
}

// ---------------------------------------------------------------------------
// Kernel 3: V[b][t][c] fp16 -> VT[b][c][t] fp16 (pure transpose; iv folded
// into attn epilogue).
// ---------------------------------------------------------------------------
__global__ __launch_bounds__(256) void norm_vt(
    const _Float16* __restrict__ V, _Float16* __restrict__ VT)
{
    const int blk = blockIdx.x;          // 4 * 8 * 32 = 1024
    const int b = blk >> 8, ct = (blk >> 5) & 7, tt = blk & 31;
    const int t0 = tt * 64, c0 = ct * 64;
    const int tid = threadIdx.x;

    __shared__ _Float16 tile[64 * 72];

#pragma unroll
    for (int i = 0; i < 2; ++i) {
        const int idx = i * 256 + tid;
        const int tr = idx >> 3, c8 = (idx & 7) * 8;
        *(f16x8*)&tile[tr * 72 + c8] =
            *(const f16x8*)&V[(size_t)(b * Tt + t0 + tr) * Cc + c0 + c8];
    }
    __syncthreads();
#pragma unroll
    for (int i = 0; i < 2; ++i) {
        const int idx = i * 256 + tid;
        const int cr = idx >> 3, t8 = (idx & 7) * 8;
        f16x8 o;
#pragma unroll
        for (int j = 0; j < 8; ++j) o[j] = tile[(t8 + j) * 72 + cr];
        *(f16x8*)&VT[(size_t)(b * Cc + c0 + cr) * Tt + t0 + t8] = o;
    }
}

// ---------------------------------------------------------------------------
// Kernel 4: fp16 MFMA flash attention, transposed (S^T / O^T) form.
// 8 waves / 512 threads: waves 0-3 (group 0) process even kv-tiles, waves
// 4-7 (group 1) odd kv-tiles; each wave keeps the round-0 shape (32 queries,
// 32 MFMA : 20 LDS-reads per tile). Max-free exp2 makes the key-split
// partials (O, l) additive; group 1 dumps partials to LDS, group 0 merges.
// LDS 73.7 KB -> 2 blocks/CU x 8 waves = 16 waves/CU (2x round 0) at
// unchanged per-wave intensity. iq*ik*scale*log2(e) folded into Q frags;
// cvt_pkrtz packs P; iv folded into epilogue.
// ---------------------------------------------------------------------------
#define LSTR 72

__global__ __launch_bounds__(512, 4) void attn_mfma(
    const _Float16* __restrict__ Qf, const _Float16* __restrict__ Kf,
    const _Float16* __restrict__ VT, const float* __restrict__ inv,
    _Float16* __restrict__ AO)
{
    const int qt = blockIdx.x;            // 16
    const int bh = blockIdx.y;            // 32
    const int b = bh >> 3, h = bh & 7;
    const int tid = threadIdx.x;
    const int wave = tid >> 6, lane = tid & 63;
    const int wg = wave & 3, grp = wave >> 2;
    const int quad = lane >> 4, lm = lane & 15;

    __shared__ _Float16 sK[2][64 * LSTR];
    __shared__ _Float16 sVT[2][64 * LSTR];
    __shared__ _Float16 sP[8 * 32 * LSTR];
    _Float16* myP = sP + wave * 32 * LSTR;
    _Float16* sKg = sK[grp];
    _Float16* sVg = sVT[grp];

    // ---- Q fragments (B-operand: n=lm=query, k=quad*8+j)
    // iq*ik*0.125*log2(e) folded -> exp2 downstream.
    f16x8 qb[2][2];
    {
        const float* iqp = inv + b * Cc + h * 64;
        const float* ikp = inv + BC + b * Cc + h * 64;
#pragma unroll
        for (int qf = 0; qf < 2; ++qf) {
            const int row = qt * 128 + wg * 32 + qf * 16 + lm;
#pragma unroll
            for (int ks = 0; ks < 2; ++ks) {
                const int d0 = ks * 32 + quad * 8;
                f16x8 qv = *(const f16x8*)&Qf[(size_t)(b * Tt + row) * Cc + h * 64 + d0];
#pragma unroll
                for (int j = 0; j < 8; ++j) {
                    const float f = (float)qv[j] * iqp[d0 + j] * ikp[d0 + j] * 0.18033688011f;
                    qb[qf][ks][j] = (_Float16)f;
                }
            }
        }
    }

    f32x4 o[4][2];      // [cf][qf]: O^T frags, m=channel, n=query
#pragma unroll
    for (int cf = 0; cf < 4; ++cf)
#pragma unroll
        for (int qf = 0; qf < 2; ++qf) o[cf][qf] = (f32x4){0.f, 0.f, 0.f, 0.f};
    float ls[2] = {0.f, 0.f};

    const int g256 = tid & 255;
    const int sr0 = g256 >> 3, sc0 = (g256 & 7) * 8;
    const int sr1 = sr0 + 32;
    const _Float16* gK = Kf + (size_t)b * Tt * Cc + h * 64;
    const _Float16* gV = VT + ((size_t)b * Cc + h * 64) * Tt;

    f16x8 rk0, rk1, rv0, rv1;
    {
        const int t0 = grp * 64;
        rk0 = *(const f16x8*)&gK[(size_t)(t0 + sr0) * Cc + sc0];
        rk1 = *(const f16x8*)&gK[(size_t)(t0 + sr1) * Cc + sc0];
        rv0 = *(const f16x8*)&gV[(size_t)sr0 * Tt + t0 + sc0];
        rv1 = *(const f16x8*)&gV[(size_t)sr1 * Tt + t0 + sc0];
    }

    for (int it = 0; it < 16; ++it) {
        __syncthreads();
        *(f16x8*)&sKg[sr0 * LSTR + sc0] = rk0;
        *(f16x8*)&sKg[sr1 * LSTR + sc0] = rk1;
        *(f16x8*)&sVg[sr0 * LSTR + sc0] = rv0;
        *(f16x8*)&sVg[sr1 * LSTR + sc0] = rv1;
        __syncthreads();

        if (it < 15) {
            const int tn = ((it + 1) * 2 + grp) * 64;
            rk0 = *(const f16x8*)&gK[(size_t)(tn + sr0) * Cc + sc0];
            rk1 = *(const f16x8*)&gK[(size_t)(tn + sr1) * Cc + sc0];
            rv0 = *(const f16x8*)&gV[(size_t)sr0 * Tt + tn + sc0];
            rv1 = *(const f16x8*)&gV[(size_t)sr1 * Tt + tn + sc0];
        }

        // ---- S^T = K Q^T  (m=key, n=query)
        f32x4 st[4][2];
#pragma unroll
        for (int kf = 0; kf < 4; ++kf)
#pragma unroll
            for (int qf = 0; qf < 2; ++qf) st[kf][qf] = (f32x4){0.f, 0.f, 0.f, 0.f};
#pragma unroll
        for (int ks = 0; ks < 2; ++ks) {
            f16x8 ka[4];
#pragma unroll
            for (int kf = 0; kf < 4; ++kf)
                ka[kf] = *(const f16x8*)&sKg[(kf * 16 + lm) * LSTR + ks * 32 + quad * 8];
#pragma unroll
            for (int kf = 0; kf < 4; ++kf)
#pragma unroll
                for (int qf = 0; qf < 2; ++qf)
                    st[kf][qf] = __builtin_amdgcn_mfma_f32_16x16x32_f16(ka[kf], qb[qf][ks], st[kf][qf], 0, 0, 0);
        }

        // ---- p = exp2(s); P rows packed b64; l partials
#pragma unroll
        for (int kf = 0; kf < 4; ++kf)
#pragma unroll
            for (int qf = 0; qf < 2; ++qf) {
                const float p0 = __builtin_amdgcn_exp2f(st[kf][qf][0]);
                const float p1 = __builtin_amdgcn_exp2f(st[kf][qf][1]);
                const float p2 = __builtin_amdgcn_exp2f(st[kf][qf][2]);
                const float p3 = __builtin_amdgcn_exp2f(st[kf][qf][3]);
                ls[qf] += (p0 + p1) + (p2 + p3);
                const f16x2 lo = __builtin_bit_cast(f16x2, __builtin_amdgcn_cvt_pkrtz(p0, p1));
                const f16x2 hi = __builtin_bit_cast(f16x2, __builtin_amdgcn_cvt_pkrtz(p2, p3));
                f16x4 pk;
                pk[0] = lo[0]; pk[1] = lo[1]; pk[2] = hi[0]; pk[3] = hi[1];
                *(f16x4*)&myP[(qf * 16 + lm) * LSTR + kf * 16 + quad * 4] = pk;
            }

        // ---- O^T += VT P^T
#pragma unroll
        for (int ks = 0; ks < 2; ++ks) {
            f16x8 pb[2];
#pragma unroll
            for (int qf = 0; qf < 2; ++qf)
                pb[qf] = *(const f16x8*)&myP[(qf * 16 + lm) * LSTR + ks * 32 + quad * 8];
            f16x8 va[4];
#pragma unroll
            for (int cf = 0; cf < 4; ++cf)
                va[cf] = *(const f16x8*)&sVg[(cf * 16 + lm) * LSTR + ks * 32 + quad * 8];
#pragma unroll
            for (int cf = 0; cf < 4; ++cf)
#pragma unroll
                for (int qf = 0; qf < 2; ++qf)
                    o[cf][qf] = __builtin_amdgcn_mfma_f32_16x16x32_f16(va[cf], pb[qf], o[cf][qf], 0, 0, 0);
        }
    }

    // ---- merge: group 1 dumps partial (O, l) to LDS; group 0 adds.
    float* fO = (float*)sP;
    float* fL = (float*)sK;
    __syncthreads();
    if (grp == 1) {
#pragma unroll
        for (int cf = 0; cf < 4; ++cf)
#pragma unroll
            for (int qf = 0; qf < 2; ++qf)
                *(f32x4*)&fO[wg * 2048 + (cf * 2 + qf) * 256 + lane * 4] = o[cf][qf];
        fL[wg * 128 + lane] = ls[0];
        fL[wg * 128 + 64 + lane] = ls[1];
    }
    __syncthreads();
    if (grp == 0) {
#pragma unroll
        for (int cf = 0; cf < 4; ++cf)
#pragma unroll
            for (int qf = 0; qf < 2; ++qf) {
                const f32x4 t = *(const f32x4*)&fO[wg * 2048 + (cf * 2 + qf) * 256 + lane * 4];
                o[cf][qf] += t;
            }
        ls[0] += fL[wg * 128 + lane];
        ls[1] += fL[wg * 128 + 64 + lane];

        // ---- epilogue: l reduce over quads, O /= l, * iv, fp16 out
        float il[2];
#pragma unroll
        for (int qf = 0; qf < 2; ++qf) {
            float s = ls[qf];
            s += __shfl_xor(s, 16, 64);
            s += __shfl_xor(s, 32, 64);
            il[qf] = 1.0f / s;
        }
        const float* ivp = inv + 2 * BC + b * Cc + h * 64;
        float iv[4][4];
#pragma unroll
        for (int cf = 0; cf < 4; ++cf) {
            float4 t = *(const float4*)&ivp[cf * 16 + quad * 4];
            iv[cf][0] = t.x; iv[cf][1] = t.y; iv[cf][2] = t.z; iv[cf][3] = t.w;
        }
#pragma unroll
        for (int qf = 0; qf < 2; ++qf) {
            const size_t row = (size_t)(b * Tt + qt * 128 + wg * 32 + qf * 16 + lm);
#pragma unroll
            for (int cf = 0; cf < 4; ++cf) {
                f16x4 pk;
#pragma unroll
                for (int r = 0; r < 4; ++r)
                    pk[r] = (_Float16)(o[cf][qf][r] * il[qf] * iv[cf][r]);
                *(f16x4*)&AO[row * Cc + h * 64 + cf * 16 + quad * 4] = pk;
            }
        }
    }
}

// ---------------------------------------------------------------------------
// Kernel 5: out = AO @ Wo + bo + residual, single-term fp16 MFMA.
// 64x128 tile, 4 waves (each 32x64).
// ---------------------------------------------------------------------------
__global__ __launch_bounds__(256, 2) void out_mfma(
    const _Float16* __restrict__ AO, const _Float16* __restrict__ Wt,
    const float* __restrict__ bo, const float* __restrict__ HS,
    float* __restrict__ Outp)
{
    const int mt = blockIdx.x;              // 128
    const int nt = blockIdx.y;              // 4
    const int tid = threadIdx.x;
    const int wave = tid >> 6, lane = tid & 63;
    const int quad = lane >> 4, lm = lane & 15;
    const int wm = (wave & 1) * 32, wn = (wave >> 1) * 64;

    __shared__ _Float16 sA[64 * 40];
    __shared__ _Float16 sB[128 * 40];

    f32x4 acc[2][4];
#pragma unroll
    for (int mf = 0; mf < 2; ++mf)
#pragma unroll
        for (int nf = 0; nf < 4; ++nf) acc[mf][nf] = (f32x4){0.f, 0.f, 0.f, 0.f};

    const int ra = tid >> 2, ka = (tid & 3) * 8;
    const int rb = tid >> 1, kb = (tid & 1) * 16;
    const _Float16* gah = AO + (size_t)(mt * 64 + ra) * Cc + ka;
    const _Float16* gbh = Wt + ((size_t)(3 * 512 + nt * 128 + rb)) * Cc + kb;

    for (int k0 = 0; k0 < Cc; k0 += 32) {
        __syncthreads();
        {
            *(f16x8*)&sA[ra * 40 + ka] = *(const f16x8*)&gah[k0];
            *(f16x8*)&sB[rb * 40 + kb]     = *(const f16x8*)&gbh[k0];
            *(f16x8*)&sB[rb * 40 + kb + 8] = *(const f16x8*)&gbh[k0 + 8];
        }
        __syncthreads();

        f16x8 ah[2], bh[4];
#pragma unroll
        for (int mf = 0; mf < 2; ++mf)
            ah[mf] = *(const f16x8*)&sA[(wm + mf * 16 + lm) * 40 + quad * 8];
#pragma unroll
        for (int nf = 0; nf < 4; ++nf)
            bh[nf] = *(const f16x8*)&sB[(wn + nf * 16 + lm) * 40 + quad * 8];
#pragma unroll
        for (int mf = 0; mf < 2; ++mf)
#pragma unroll
            for (int nf = 0; nf < 4; ++nf)
                acc[mf][nf] = __builtin_amdgcn_mfma_f32_16x16x32_f16(ah[mf], bh[nf], acc[mf][nf], 0, 0, 0);
    }

#pragma unroll
    for (int mf = 0; mf < 2; ++mf)
#pragma unroll
        for (int r = 0; r < 4; ++r) {
            const size_t m = (size_t)(mt * 64 + wm + mf * 16 + quad * 4 + r);
#pragma unroll
            for (int nf = 0; nf < 4; ++nf) {
                const int col = nt * 128 + wn + nf * 16 + lm;
                Outp[m * Cc + col] = acc[mf][nf][r] + bo[col] + HS[m * Cc + col];
            }
        }
}

// ---------------------------------------------------------------------------
extern "C" void kernel_launch(void* const* d_in, const int* in_sizes, int n_in,
                              void* d_out, int out_size, void* d_ws,
                              size_t ws_size, hipStream_t stream)
{
    const float* HS = (const float*)d_in[0];
    const float* Wq = (const float*)d_in[1];
    const float* Wk = (const float*)d_in[2];
    const float* Wv = (const float*)d_in[3];
    const float* Wo = (const float*)d_in[4];
    const float* bo = (const float*)d_in[5];
    float* out = (float*)d_out;

    const size_t SZ = (size_t)Bb * Tt * Cc;        // 4,194,304 elements
    _Float16* Qf  = (_Float16*)d_ws;
    _Float16* Kf  = Qf + SZ;
    _Float16* Vf  = Kf + SZ;
    _Float16* VTh = Vf + SZ;
    _Float16* AO  = VTh + SZ;
    _Float16* Wt  = AO + SZ;                        // 4*Cc*Cc halves
    float* colsum = (float*)(Wt + 4 * Cc * Cc);
    float* inv    = colsum + 3 * BC;

    (void)hipMemsetAsync(colsum, 0, 3 * BC * sizeof(float), stream);

    wsetup<<<dim3(64, 4), 256, 0, stream>>>(Wq, Wk, Wv, Wo, Wt);

    qkv_mfma<<<dim3(64, 4, 3), 256, 0, stream>>>(HS, Wt, Qf, Kf, Vf, colsum);

    inv_norm_kernel<<<(3 * BC + 255) / 256, 256, 0, stream>>>(colsum, inv);

    norm_vt<<<1024, 256, 0, stream>>>(Vf, VTh);

    attn_mfma<<<dim3(16, 32), 512, 0, stream>>>(Qf, Kf, VTh, inv, AO);

    out_mfma<<<dim3(128, 4), 256, 0, stream>>>(AO, Wt, bo, HS, out);
}

// Round 4
// 181.606 us; speedup vs baseline: 1.0616x; 1.0616x over previous
//
#include <hip/hip_runtime.h>

#define Tt 2048
#define Cc 512
#define Bb 4
#define BC (Bb * Cc)

typedef __attribute__((ext_vector_type(4))) float f32x4;
typedef __attribute__((ext_vector_type(8))) _Float16 f16x8;
typedef __attribute__((ext_vector_type(4))) _Float16 f16x4;
typedef __attribute__((ext_vector_type(2))) _Float16 f16x2;

// ---------------------------------------------------------------------------
// Kernel 0: W[k][n] (x4) -> Wt[z][n][k] fp16 (single plane).
// ---------------------------------------------------------------------------
__global__ __launch_bounds__(256) void wsetup(
    const float* __restrict__ Wq, const float* __restrict__ Wk,
    const float* __restrict__ Wv, const float* __restrict__ Wo,
    _Float16* __restrict__ Wt)
{
    const int z = blockIdx.y;
    const float* W = (z == 0) ? Wq : (z == 1) ? Wk : (z == 2) ? Wv : Wo;
    const int k0 = (blockIdx.x >> 3) * 64, n0 = (blockIdx.x & 7) * 64;
    const int tid = threadIdx.x;
    __shared__ float tile[64][65];

#pragma unroll
    for (int i = 0; i < 4; ++i) {
        const int idx = i * 256 + tid;
        const int kr = idx >> 4, c4 = idx & 15;
        float4 v = *(const float4*)&W[(size_t)(k0 + kr) * Cc + n0 + c4 * 4];
        tile[kr][c4 * 4 + 0] = v.x; tile[kr][c4 * 4 + 1] = v.y;
        tile[kr][c4 * 4 + 2] = v.z; tile[kr][c4 * 4 + 3] = v.w;
    }
    __syncthreads();
#pragma unroll
    for (int i = 0; i < 4; ++i) {
        const int idx = i * 256 + tid;
        const int nr = idx >> 4, k4 = idx & 15;
        f16x4 o;
        o[0] = (_Float16)tile[k4 * 4 + 0][nr];
        o[1] = (_Float16)tile[k4 * 4 + 1][nr];
        o[2] = (_Float16)tile[k4 * 4 + 2][nr];
        o[3] = (_Float16)tile[k4 * 4 + 3][nr];
        *(f16x4*)&Wt[((size_t)(z * 512 + n0 + nr)) * Cc + k0 + k4 * 4] = o;
    }
}

// ---------------------------------------------------------------------------
// Kernel 1: QKV GEMM, single-term fp16 MFMA. 128x128 tile, 4 waves, BK=32.
// Epilogue: fp16 store + per-(b,channel) column sum-of-squares (fp32 acc).
// ---------------------------------------------------------------------------
__global__ __launch_bounds__(256, 3) void qkv_mfma(
    const float* __restrict__ HS, const _Float16* __restrict__ Wt,
    _Float16* __restrict__ Qf, _Float16* __restrict__ Kf,
    _Float16* __restrict__ Vf, float* __restrict__ colsum)
{
    const int mt = blockIdx.x;              // 64
    const int nt = blockIdx.y;              // 4
    const int z  = blockIdx.z;              // 3
    _Float16* Out = (z == 0) ? Qf : (z == 1) ? Kf : Vf;

    const int tid = threadIdx.x;
    const int wave = tid >> 6, lane = tid & 63;
    const int quad = lane >> 4, lm = lane & 15;
    const int wm = (wave & 1) * 64, wn = (wave >> 1) * 64;

    __shared__ _Float16 sA[128 * 40];
    __shared__ _Float16 sB[128 * 40];

    f32x4 acc[4][4];
#pragma unroll
    for (int mf = 0; mf < 4; ++mf)
#pragma unroll
        for (int nf = 0; nf < 4; ++nf) acc[mf][nf] = (f32x4){0.f, 0.f, 0.f, 0.f};

    const int r2 = tid >> 1, kc = (tid & 1) * 16;
    const float* ga = HS + (size_t)(mt * 128 + r2) * Cc + kc;
    const _Float16* gb = Wt + ((size_t)(z * 512 + nt * 128 + r2)) * Cc + kc;

    for (int k0 = 0; k0 < Cc; k0 += 32) {
        __syncthreads();
        {
            float4 a0 = *(const float4*)&ga[k0];
            float4 a1 = *(const float4*)&ga[k0 + 4];
            float4 a2 = *(const float4*)&ga[k0 + 8];
            float4 a3 = *(const float4*)&ga[k0 + 12];
            f16x8 h0, h1;
            h0[0] = (_Float16)a0.x; h0[1] = (_Float16)a0.y;
            h0[2] = (_Float16)a0.z; h0[3] = (_Float16)a0.w;
            h0[4] = (_Float16)a1.x; h0[5] = (_Float16)a1.y;
            h0[6] = (_Float16)a1.z; h0[7] = (_Float16)a1.w;
            h1[0] = (_Float16)a2.x; h1[1] = (_Float16)a2.y;
            h1[2] = (_Float16)a2.z; h1[3] = (_Float16)a2.w;
            h1[4] = (_Float16)a3.x; h1[5] = (_Float16)a3.y;
            h1[6] = (_Float16)a3.z; h1[7] = (_Float16)a3.w;
            *(f16x8*)&sA[r2 * 40 + kc]     = h0;
            *(f16x8*)&sA[r2 * 40 + kc + 8] = h1;
            *(f16x8*)&sB[r2 * 40 + kc]     = *(const f16x8*)&gb[k0];
            *(f16x8*)&sB[r2 * 40 + kc + 8] = *(const f16x8*)&gb[k0 + 8];
        }
        __syncthreads();

        f16x8 ah[4], bh[4];
#pragma unroll
        for (int mf = 0; mf < 4; ++mf)
            ah[mf] = *(const f16x8*)&sA[(wm + mf * 16 + lm) * 40 + quad * 8];
#pragma unroll
        for (int nf = 0; nf < 4; ++nf)
            bh[nf] = *(const f16x8*)&sB[(wn + nf * 16 + lm) * 40 + quad * 8];
#pragma unroll
        for (int mf = 0; mf < 4; ++mf)
#pragma unroll
            for (int nf = 0; nf < 4; ++nf)
                acc[mf][nf] = __builtin_amdgcn_mfma_f32_16x16x32_f16(ah[mf], bh[nf], acc[mf][nf], 0, 0, 0);
    }

    const int bidx = mt >> 4;
#pragma unroll
    for (int nf = 0; nf < 4; ++nf) {
        float cs = 0.f;
#pragma unroll
        for (int mf = 0; mf < 4; ++mf)
#pragma unroll
            for (int r = 0; r < 4; ++r) {
                const float v = acc[mf][nf][r];
                const size_t idx =
                    (size_t)(mt * 128 + wm + mf * 16 + quad * 4 + r) * Cc +
                    nt * 128 + wn + nf * 16 + lm;
                Out[idx] = (_Float16)v;
                cs += v * v;
            }
        cs += __shfl_xor(cs, 16, 64);
        cs += __shfl_xor(cs, 32, 64);
        if (lane < 16)
            atomicAdd(&colsum[(size_t)z * BC + bidx * Cc + nt * 128 + wn + nf * 16 + lane], cs);
    }
}

// ---------------------------------------------------------------------------
// Kernel 2: colsum -> 1/sqrt(mean + eps)
// ---------------------------------------------------------------------------
__global__ void inv_norm_kernel(const float* __restrict__ colsum,
                                float* __restrict__ inv)
{
    const int i = blockIdx.x * blockDim.x + threadIdx.x;
    if (i < 3 * BC) inv[i] = rsqrtf(colsum[i] * (1.0f / Tt) + 1e-4f);
}

// ---------------------------------------------------------------------------
// Kernel 3: V[b][t][c] fp16 -> VT[b][c][t] fp16 (pure transpose; iv folded
// into attn epilogue).
// ---------------------------------------------------------------------------
__global__ __launch_bounds__(256) void norm_vt(
    const _Float16* __restrict__ V, _Float16* __restrict__ VT)
{
    const int blk = blockIdx.x;          // 4 * 8 * 32 = 1024
    const int b = blk >> 8, ct = (blk >> 5) & 7, tt = blk & 31;
    const int t0 = tt * 64, c0 = ct * 64;
    const int tid = threadIdx.x;

    __shared__ _Float16 tile[64 * 72];

#pragma unroll
    for (int i = 0; i < 2; ++i) {
        const int idx = i * 256 + tid;
        const int tr = idx >> 3, c8 = (idx & 7) * 8;
        *(f16x8*)&tile[tr * 72 + c8] =
            *(const f16x8*)&V[(size_t)(b * Tt + t0 + tr) * Cc + c0 + c8];
    }
    __syncthreads();
#pragma unroll
    for (int i = 0; i < 2; ++i) {
        const int idx = i * 256 + tid;
        const int cr = idx >> 3, t8 = (idx & 7) * 8;
        f16x8 o;
#pragma unroll
        for (int j = 0; j < 8; ++j) o[j] = tile[(t8 + j) * 72 + cr];
        *(f16x8*)&VT[(size_t)(b * Cc + c0 + cr) * Tt + t0 + t8] = o;
    }
}

// ---------------------------------------------------------------------------
// Kernel 4: fp16 MFMA flash attention, transposed (S^T / O^T) form.
// 4 waves, 32 queries/wave (round-0 shape). Cross-iteration software
// pipeline: iter kt does QK(kt) [MFMA], PV(kt-1) [MFMA], exp(kt) [VALU];
// exp(kt) and PV(kt-1) are independent -> VALU/MFMA overlap instead of
// lockstep phase alternation. P (per-wave, barrier-free) and V tiles
// double-buffered. l accumulated via ones-MFMA (kills serial VALU adds +
// epilogue shuffle). 1-D grid, bid = qt*32+bh: all 16 qt-blocks of one bh
// share bid%8 -> one XCD -> K/V panels (2 MB/XCD) L2-resident.
// iq*ik*scale*log2(e) folded into Q frags -> exp2; cvt_pkrtz packs P;
// iv folded into epilogue.
// ---------------------------------------------------------------------------
#define LSTR 72

__global__ __launch_bounds__(256, 2) void attn_mfma(
    const _Float16* __restrict__ Qf, const _Float16* __restrict__ Kf,
    const _Float16* __restrict__ VT, const float* __restrict__ inv,
    _Float16* __restrict__ AO)
{
    const int bid = blockIdx.x;           // 512
    const int qt = bid >> 5;              // 16
    const int bh = bid & 31;              // 32 (bid%8 == bh%8 -> XCD locality)
    const int b = bh >> 3, h = bh & 7;
    const int tid = threadIdx.x;
    const int wave = tid >> 6, lane = tid & 63;
    const int quad = lane >> 4, lm = lane & 15;

    __shared__ _Float16 sK[2][64 * LSTR];
    __shared__ _Float16 sVT[2][64 * LSTR];
    __shared__ _Float16 sP[2][4][32 * LSTR];

    // ---- Q fragments (B-operand: n=lm=query, k=quad*8+j)
    // iq*ik*0.125*log2(e) folded -> exp2 downstream.
    f16x8 qb[2][2];
    {
        const float* iqp = inv + b * Cc + h * 64;
        const float* ikp = inv + BC + b * Cc + h * 64;
#pragma unroll
        for (int qf = 0; qf < 2; ++qf) {
            const int row = qt * 128 + wave * 32 + qf * 16 + lm;
#pragma unroll
            for (int ks = 0; ks < 2; ++ks) {
                const int d0 = ks * 32 + quad * 8;
                f16x8 qv = *(const f16x8*)&Qf[(size_t)(b * Tt + row) * Cc + h * 64 + d0];
#pragma unroll
                for (int j = 0; j < 8; ++j) {
                    const float f = (float)qv[j] * iqp[d0 + j] * ikp[d0 + j] * 0.18033688011f;
                    qb[qf][ks][j] = (_Float16)f;
                }
            }
        }
    }

    f32x4 o[4][2];      // [cf][qf]: O^T frags, m=channel, n=query
#pragma unroll
    for (int cf = 0; cf < 4; ++cf)
#pragma unroll
        for (int qf = 0; qf < 2; ++qf) o[cf][qf] = (f32x4){0.f, 0.f, 0.f, 0.f};
    f32x4 ol[2];        // l accumulators via ones-MFMA (all elems = l[query])
#pragma unroll
    for (int qf = 0; qf < 2; ++qf) ol[qf] = (f32x4){0.f, 0.f, 0.f, 0.f};
    f16x8 ones;
#pragma unroll
    for (int j = 0; j < 8; ++j) ones[j] = (_Float16)1.0f;

    const int sr0 = tid >> 3, sc0 = (tid & 7) * 8;
    const int sr1 = sr0 + 32;
    const _Float16* gK = Kf + (size_t)b * Tt * Cc + h * 64;
    const _Float16* gV = VT + ((size_t)b * Cc + h * 64) * Tt;

    f16x8 rk0, rk1, rv0, rv1;
    {
        rk0 = *(const f16x8*)&gK[(size_t)sr0 * Cc + sc0];
        rk1 = *(const f16x8*)&gK[(size_t)sr1 * Cc + sc0];
        rv0 = *(const f16x8*)&gV[(size_t)sr0 * Tt + sc0];
        rv1 = *(const f16x8*)&gV[(size_t)sr1 * Tt + sc0];
    }

    for (int kt = 0; kt < 32; ++kt) {
        const int cur = kt & 1, prv = cur ^ 1;
        _Float16* sKc = sK[cur];
        _Float16* sVc = sVT[cur];
        _Float16* myPc = &sP[cur][wave][0];
        _Float16* myPp = &sP[prv][wave][0];

        __syncthreads();
        *(f16x8*)&sKc[sr0 * LSTR + sc0] = rk0;
        *(f16x8*)&sKc[sr1 * LSTR + sc0] = rk1;
        *(f16x8*)&sVc[sr0 * LSTR + sc0] = rv0;
        *(f16x8*)&sVc[sr1 * LSTR + sc0] = rv1;
        __syncthreads();

        if (kt < 31) {
            const int t0 = (kt + 1) * 64;
            rk0 = *(const f16x8*)&gK[(size_t)(t0 + sr0) * Cc + sc0];
            rk1 = *(const f16x8*)&gK[(size_t)(t0 + sr1) * Cc + sc0];
            rv0 = *(const f16x8*)&gV[(size_t)sr0 * Tt + t0 + sc0];
            rv1 = *(const f16x8*)&gV[(size_t)sr1 * Tt + t0 + sc0];
        }

        // ---- S^T(kt) = K Q^T  (m=key, n=query)
        f32x4 st[4][2];
#pragma unroll
        for (int kf = 0; kf < 4; ++kf)
#pragma unroll
            for (int qf = 0; qf < 2; ++qf) st[kf][qf] = (f32x4){0.f, 0.f, 0.f, 0.f};
#pragma unroll
        for (int ks = 0; ks < 2; ++ks) {
            f16x8 ka[4];
#pragma unroll
            for (int kf = 0; kf < 4; ++kf)
                ka[kf] = *(const f16x8*)&sKc[(kf * 16 + lm) * LSTR + ks * 32 + quad * 8];
#pragma unroll
            for (int kf = 0; kf < 4; ++kf)
#pragma unroll
                for (int qf = 0; qf < 2; ++qf)
                    st[kf][qf] = __builtin_amdgcn_mfma_f32_16x16x32_f16(ka[kf], qb[qf][ks], st[kf][qf], 0, 0, 0);
        }

        // ---- PV(kt-1): O^T += VT P^T ; l += ones P^T  (independent of st)
        if (kt > 0) {
            _Float16* sVp = sVT[prv];
#pragma unroll
            for (int ks = 0; ks < 2; ++ks) {
                f16x8 pb[2];
#pragma unroll
                for (int qf = 0; qf < 2; ++qf)
                    pb[qf] = *(const f16x8*)&myPp[(qf * 16 + lm) * LSTR + ks * 32 + quad * 8];
                f16x8 va[4];
#pragma unroll
                for (int cf = 0; cf < 4; ++cf)
                    va[cf] = *(const f16x8*)&sVp[(cf * 16 + lm) * LSTR + ks * 32 + quad * 8];
#pragma unroll
                for (int cf = 0; cf < 4; ++cf)
#pragma unroll
                    for (int qf = 0; qf < 2; ++qf)
                        o[cf][qf] = __builtin_amdgcn_mfma_f32_16x16x32_f16(va[cf], pb[qf], o[cf][qf], 0, 0, 0);
#pragma unroll
                for (int qf = 0; qf < 2; ++qf)
                    ol[qf] = __builtin_amdgcn_mfma_f32_16x16x32_f16(ones, pb[qf], ol[qf], 0, 0, 0);
            }
        }

        // ---- p = exp2(s(kt)); pack to sP[cur]
#pragma unroll
        for (int kf = 0; kf < 4; ++kf)
#pragma unroll
            for (int qf = 0; qf < 2; ++qf) {
                const float p0 = __builtin_amdgcn_exp2f(st[kf][qf][0]);
                const float p1 = __builtin_amdgcn_exp2f(st[kf][qf][1]);
                const float p2 = __builtin_amdgcn_exp2f(st[kf][qf][2]);
                const float p3 = __builtin_amdgcn_exp2f(st[kf][qf][3]);
                const f16x2 lo = __builtin_bit_cast(f16x2, __builtin_amdgcn_cvt_pkrtz(p0, p1));
                const f16x2 hi = __builtin_bit_cast(f16x2, __builtin_amdgcn_cvt_pkrtz(p2, p3));
                f16x4 pk;
                pk[0] = lo[0]; pk[1] = lo[1]; pk[2] = hi[0]; pk[3] = hi[1];
                *(f16x4*)&myPc[(qf * 16 + lm) * LSTR + kf * 16 + quad * 4] = pk;
            }
    }

    // ---- drain PV(31): P in sP[1], V in sVT[1]
    {
        _Float16* myPp = &sP[1][wave][0];
        _Float16* sVp = sVT[1];
#pragma unroll
        for (int ks = 0; ks < 2; ++ks) {
            f16x8 pb[2];
#pragma unroll
            for (int qf = 0; qf < 2; ++qf)
                pb[qf] = *(const f16x8*)&myPp[(qf * 16 + lm) * LSTR + ks * 32 + quad * 8];
            f16x8 va[4];
#pragma unroll
            for (int cf = 0; cf < 4; ++cf)
                va[cf] = *(const f16x8*)&sVp[(cf * 16 + lm) * LSTR + ks * 32 + quad * 8];
#pragma unroll
            for (int cf = 0; cf < 4; ++cf)
#pragma unroll
                for (int qf = 0; qf < 2; ++qf)
                    o[cf][qf] = __builtin_amdgcn_mfma_f32_16x16x32_f16(va[cf], pb[qf], o[cf][qf], 0, 0, 0);
#pragma unroll
            for (int qf = 0; qf < 2; ++qf)
                ol[qf] = __builtin_amdgcn_mfma_f32_16x16x32_f16(ones, pb[qf], ol[qf], 0, 0, 0);
        }
    }

    // ---- epilogue: il from ones-MFMA acc, O *= il * iv (per-channel), fp16
    float il[2];
#pragma unroll
    for (int qf = 0; qf < 2; ++qf) il[qf] = 1.0f / ol[qf][0];
    const float* ivp = inv + 2 * BC + b * Cc + h * 64;
    float iv[4][4];
#pragma unroll
    for (int cf = 0; cf < 4; ++cf) {
        float4 t = *(const float4*)&ivp[cf * 16 + quad * 4];
        iv[cf][0] = t.x; iv[cf][1] = t.y; iv[cf][2] = t.z; iv[cf][3] = t.w;
    }
#pragma unroll
    for (int qf = 0; qf < 2; ++qf) {
        const size_t row = (size_t)(b * Tt + qt * 128 + wave * 32 + qf * 16 + lm);
#pragma unroll
        for (int cf = 0; cf < 4; ++cf) {
            f16x4 pk;
#pragma unroll
            for (int r = 0; r < 4; ++r)
                pk[r] = (_Float16)(o[cf][qf][r] * il[qf] * iv[cf][r]);
            *(f16x4*)&AO[row * Cc + h * 64 + cf * 16 + quad * 4] = pk;
        }
    }
}

// ---------------------------------------------------------------------------
// Kernel 5: out = AO @ Wo + bo + residual, single-term fp16 MFMA.
// 64x128 tile, 4 waves (each 32x64).
// ---------------------------------------------------------------------------
__global__ __launch_bounds__(256, 2) void out_mfma(
    const _Float16* __restrict__ AO, const _Float16* __restrict__ Wt,
    const float* __restrict__ bo, const float* __restrict__ HS,
    float* __restrict__ Outp)
{
    const int mt = blockIdx.x;              // 128
    const int nt = blockIdx.y;              // 4
    const int tid = threadIdx.x;
    const int wave = tid >> 6, lane = tid & 63;
    const int quad = lane >> 4, lm = lane & 15;
    const int wm = (wave & 1) * 32, wn = (wave >> 1) * 64;

    __shared__ _Float16 sA[64 * 40];
    __shared__ _Float16 sB[128 * 40];

    f32x4 acc[2][4];
#pragma unroll
    for (int mf = 0; mf < 2; ++mf)
#pragma unroll
        for (int nf = 0; nf < 4; ++nf) acc[mf][nf] = (f32x4){0.f, 0.f, 0.f, 0.f};

    const int ra = tid >> 2, ka = (tid & 3) * 8;
    const int rb = tid >> 1, kb = (tid & 1) * 16;
    const _Float16* gah = AO + (size_t)(mt * 64 + ra) * Cc + ka;
    const _Float16* gbh = Wt + ((size_t)(3 * 512 + nt * 128 + rb)) * Cc + kb;

    for (int k0 = 0; k0 < Cc; k0 += 32) {
        __syncthreads();
        {
            *(f16x8*)&sA[ra * 40 + ka] = *(const f16x8*)&gah[k0];
            *(f16x8*)&sB[rb * 40 + kb]     = *(const f16x8*)&gbh[k0];
            *(f16x8*)&sB[rb * 40 + kb + 8] = *(const f16x8*)&gbh[k0 + 8];
        }
        __syncthreads();

        f16x8 ah[2], bh[4];
#pragma unroll
        for (int mf = 0; mf < 2; ++mf)
            ah[mf] = *(const f16x8*)&sA[(wm + mf * 16 + lm) * 40 + quad * 8];
#pragma unroll
        for (int nf = 0; nf < 4; ++nf)
            bh[nf] = *(const f16x8*)&sB[(wn + nf * 16 + lm) * 40 + quad * 8];
#pragma unroll
        for (int mf = 0; mf < 2; ++mf)
#pragma unroll
            for (int nf = 0; nf < 4; ++nf)
                acc[mf][nf] = __builtin_amdgcn_mfma_f32_16x16x32_f16(ah[mf], bh[nf], acc[mf][nf], 0, 0, 0);
    }

#pragma unroll
    for (int mf = 0; mf < 2; ++mf)
#pragma unroll
        for (int r = 0; r < 4; ++r) {
            const size_t m = (size_t)(mt * 64 + wm + mf * 16 + quad * 4 + r);
#pragma unroll
            for (int nf = 0; nf < 4; ++nf) {
                const int col = nt * 128 + wn + nf * 16 + lm;
                Outp[m * Cc + col] = acc[mf][nf][r] + bo[col] + HS[m * Cc + col];
            }
        }
}

// ---------------------------------------------------------------------------
extern "C" void kernel_launch(void* const* d_in, const int* in_sizes, int n_in,
                              void* d_out, int out_size, void* d_ws,
                              size_t ws_size, hipStream_t stream)
{
    const float* HS = (const float*)d_in[0];
    const float* Wq = (const float*)d_in[1];
    const float* Wk = (const float*)d_in[2];
    const float* Wv = (const float*)d_in[3];
    const float* Wo = (const float*)d_in[4];
    const float* bo = (const float*)d_in[5];
    float* out = (float*)d_out;

    const size_t SZ = (size_t)Bb * Tt * Cc;        // 4,194,304 elements
    _Float16* Qf  = (_Float16*)d_ws;
    _Float16* Kf  = Qf + SZ;
    _Float16* Vf  = Kf + SZ;
    _Float16* VTh = Vf + SZ;
    _Float16* AO  = VTh + SZ;
    _Float16* Wt  = AO + SZ;                        // 4*Cc*Cc halves
    float* colsum = (float*)(Wt + 4 * Cc * Cc);
    float* inv    = colsum + 3 * BC;

    (void)hipMemsetAsync(colsum, 0, 3 * BC * sizeof(float), stream);

    wsetup<<<dim3(64, 4), 256, 0, stream>>>(Wq, Wk, Wv, Wo, Wt);

    qkv_mfma<<<dim3(64, 4, 3), 256, 0, stream>>>(HS, Wt, Qf, Kf, Vf, colsum);

    inv_norm_kernel<<<(3 * BC + 255) / 256, 256, 0, stream>>>(colsum, inv);

    norm_vt<<<1024, 256, 0, stream>>>(Vf, VTh);

    attn_mfma<<<dim3(512), 256, 0, stream>>>(Qf, Kf, VTh, inv, AO);

    out_mfma<<<dim3(128, 4), 256, 0, stream>>>(AO, Wt, bo, HS, out);
}

// Round 5
// 166.950 us; speedup vs baseline: 1.1548x; 1.0878x over previous
//
#include <hip/hip_runtime.h>

#define Tt 2048
#define Cc 512
#define Bb 4
#define BC (Bb * Cc)

typedef __attribute__((ext_vector_type(4))) float f32x4;
typedef __attribute__((ext_vector_type(8))) _Float16 f16x8;
typedef __attribute__((ext_vector_type(4))) _Float16 f16x4;
typedef __attribute__((ext_vector_type(2))) _Float16 f16x2;

// ---------------------------------------------------------------------------
// Kernel 0: W[k][n] (x4) -> Wt[z][n][k] fp16 (single plane).
// ---------------------------------------------------------------------------
__global__ __launch_bounds__(256) void wsetup(
    const float* __restrict__ Wq, const float* __restrict__ Wk,
    const float* __restrict__ Wv, const float* __restrict__ Wo,
    _Float16* __restrict__ Wt)
{
    const int z = blockIdx.y;
    const float* W = (z == 0) ? Wq : (z == 1) ? Wk : (z == 2) ? Wv : Wo;
    const int k0 = (blockIdx.x >> 3) * 64, n0 = (blockIdx.x & 7) * 64;
    const int tid = threadIdx.x;
    __shared__ float tile[64][65];

#pragma unroll
    for (int i = 0; i < 4; ++i) {
        const int idx = i * 256 + tid;
        const int kr = idx >> 4, c4 = idx & 15;
        float4 v = *(const float4*)&W[(size_t)(k0 + kr) * Cc + n0 + c4 * 4];
        tile[kr][c4 * 4 + 0] = v.x; tile[kr][c4 * 4 + 1] = v.y;
        tile[kr][c4 * 4 + 2] = v.z; tile[kr][c4 * 4 + 3] = v.w;
    }
    __syncthreads();
#pragma unroll
    for (int i = 0; i < 4; ++i) {
        const int idx = i * 256 + tid;
        const int nr = idx >> 4, k4 = idx & 15;
        f16x4 o;
        o[0] = (_Float16)tile[k4 * 4 + 0][nr];
        o[1] = (_Float16)tile[k4 * 4 + 1][nr];
        o[2] = (_Float16)tile[k4 * 4 + 2][nr];
        o[3] = (_Float16)tile[k4 * 4 + 3][nr];
        *(f16x4*)&Wt[((size_t)(z * 512 + n0 + nr)) * Cc + k0 + k4 * 4] = o;
    }
}

// ---------------------------------------------------------------------------
// Kernel 0b: HS fp32 -> fp16 (one shot; removes per-z re-read + per-iter
// cvt VALU from qkv staging). 2048 blocks x 256 thr x 8 elems.
// ---------------------------------------------------------------------------
__global__ __launch_bounds__(256) void hs_half(
    const float* __restrict__ HS, _Float16* __restrict__ HSh)
{
    const size_t i = ((size_t)blockIdx.x * 256 + threadIdx.x) * 8;
    float4 a = *(const float4*)&HS[i];
    float4 b = *(const float4*)&HS[i + 4];
    f16x8 o;
    o[0] = (_Float16)a.x; o[1] = (_Float16)a.y;
    o[2] = (_Float16)a.z; o[3] = (_Float16)a.w;
    o[4] = (_Float16)b.x; o[5] = (_Float16)b.y;
    o[6] = (_Float16)b.z; o[7] = (_Float16)b.w;
    *(f16x8*)&HSh[i] = o;
}

// ---------------------------------------------------------------------------
// Kernel 1: QKV GEMM, single-term fp16 MFMA. 128x128 tile, 4 waves, BK=32.
// A-operand read from pre-converted fp16 HSh.
// Epilogue: fp16 store + per-(b,channel) column sum-of-squares (fp32 acc).
// ---------------------------------------------------------------------------
__global__ __launch_bounds__(256, 3) void qkv_mfma(
    const _Float16* __restrict__ HSh, const _Float16* __restrict__ Wt,
    _Float16* __restrict__ Qf, _Float16* __restrict__ Kf,
    _Float16* __restrict__ Vf, float* __restrict__ colsum)
{
    const int mt = blockIdx.x;              // 64
    const int nt = blockIdx.y;              // 4
    const int z  = blockIdx.z;              // 3
    _Float16* Out = (z == 0) ? Qf : (z == 1) ? Kf : Vf;

    const int tid = threadIdx.x;
    const int wave = tid >> 6, lane = tid & 63;
    const int quad = lane >> 4, lm = lane & 15;
    const int wm = (wave & 1) * 64, wn = (wave >> 1) * 64;

    __shared__ _Float16 sA[128 * 40];
    __shared__ _Float16 sB[128 * 40];

    f32x4 acc[4][4];
#pragma unroll
    for (int mf = 0; mf < 4; ++mf)
#pragma unroll
        for (int nf = 0; nf < 4; ++nf) acc[mf][nf] = (f32x4){0.f, 0.f, 0.f, 0.f};

    const int r2 = tid >> 1, kc = (tid & 1) * 16;
    const _Float16* ga = HSh + (size_t)(mt * 128 + r2) * Cc + kc;
    const _Float16* gb = Wt + ((size_t)(z * 512 + nt * 128 + r2)) * Cc + kc;

    for (int k0 = 0; k0 < Cc; k0 += 32) {
        __syncthreads();
        {
            *(f16x8*)&sA[r2 * 40 + kc]     = *(const f16x8*)&ga[k0];
            *(f16x8*)&sA[r2 * 40 + kc + 8] = *(const f16x8*)&ga[k0 + 8];
            *(f16x8*)&sB[r2 * 40 + kc]     = *(const f16x8*)&gb[k0];
            *(f16x8*)&sB[r2 * 40 + kc + 8] = *(const f16x8*)&gb[k0 + 8];
        }
        __syncthreads();

        f16x8 ah[4], bh[4];
#pragma unroll
        for (int mf = 0; mf < 4; ++mf)
            ah[mf] = *(const f16x8*)&sA[(wm + mf * 16 + lm) * 40 + quad * 8];
#pragma unroll
        for (int nf = 0; nf < 4; ++nf)
            bh[nf] = *(const f16x8*)&sB[(wn + nf * 16 + lm) * 40 + quad * 8];
#pragma unroll
        for (int mf = 0; mf < 4; ++mf)
#pragma unroll
            for (int nf = 0; nf < 4; ++nf)
                acc[mf][nf] = __builtin_amdgcn_mfma_f32_16x16x32_f16(ah[mf], bh[nf], acc[mf][nf], 0, 0, 0);
    }

    const int bidx = mt >> 4;
#pragma unroll
    for (int nf = 0; nf < 4; ++nf) {
        float cs = 0.f;
#pragma unroll
        for (int mf = 0; mf < 4; ++mf)
#pragma unroll
            for (int r = 0; r < 4; ++r) {
                const float v = acc[mf][nf][r];
                const size_t idx =
                    (size_t)(mt * 128 + wm + mf * 16 + quad * 4 + r) * Cc +
                    nt * 128 + wn + nf * 16 + lm;
                Out[idx] = (_Float16)v;
                cs += v * v;
            }
        cs += __shfl_xor(cs, 16, 64);
        cs += __shfl_xor(cs, 32, 64);
        if (lane < 16)
            atomicAdd(&colsum[(size_t)z * BC + bidx * Cc + nt * 128 + wn + nf * 16 + lane], cs);
    }
}

// ---------------------------------------------------------------------------
// Kernel 2: colsum -> 1/sqrt(mean + eps)
// ---------------------------------------------------------------------------
__global__ void inv_norm_kernel(const float* __restrict__ colsum,
                                float* __restrict__ inv)
{
    const int i = blockIdx.x * blockDim.x + threadIdx.x;
    if (i < 3 * BC) inv[i] = rsqrtf(colsum[i] * (1.0f / Tt) + 1e-4f);
}

// ---------------------------------------------------------------------------
// Kernel 3: V[b][t][c] fp16 -> VT[b][c][t'] fp16 with key-permuted t within
// each 64-block: t = b5*32 + u*16 + q*4 + r  ->  t' = b5*32 + q*8 + u*4 + r.
// This makes the attn PV B-operand (P) lane-local to the QK output fragment
// (no LDS round-trip for P). Pure transpose otherwise; iv folded into attn
// epilogue.
// ---------------------------------------------------------------------------
__global__ __launch_bounds__(256) void norm_vt(
    const _Float16* __restrict__ V, _Float16* __restrict__ VT)
{
    const int blk = blockIdx.x;          // 4 * 8 * 32 = 1024
    const int b = blk >> 8, ct = (blk >> 5) & 7, tt = blk & 31;
    const int t0 = tt * 64, c0 = ct * 64;
    const int tid = threadIdx.x;

    __shared__ _Float16 tile[64 * 72];

#pragma unroll
    for (int i = 0; i < 2; ++i) {
        const int idx = i * 256 + tid;
        const int tr = idx >> 3, c8 = (idx & 7) * 8;
        *(f16x8*)&tile[tr * 72 + c8] =
            *(const f16x8*)&V[(size_t)(b * Tt + t0 + tr) * Cc + c0 + c8];
    }
    __syncthreads();
#pragma unroll
    for (int i = 0; i < 2; ++i) {
        const int idx = i * 256 + tid;
        const int cr = idx >> 3, u = idx & 7;   // u = keys [u*8, u*8+7]
        // dest base for this 8-key group under the kappa permutation:
        const int C0 = ((u >> 2) & 1) * 32 + (u & 1) * 16 + ((u >> 1) & 1) * 4;
        f16x4 oa, ob;
#pragma unroll
        for (int j = 0; j < 4; ++j) oa[j] = tile[(u * 8 + j) * 72 + cr];
#pragma unroll
        for (int j = 0; j < 4; ++j) ob[j] = tile[(u * 8 + 4 + j) * 72 + cr];
        _Float16* dst = &VT[(size_t)(b * Cc + c0 + cr) * Tt + t0];
        *(f16x4*)&dst[C0]     = oa;
        *(f16x4*)&dst[C0 + 8] = ob;
    }
}

// ---------------------------------------------------------------------------
// Kernel 4: fp16 MFMA flash attention, transposed (S^T / O^T) form.
// 4 waves, 32 queries/wave. Cross-iteration pipeline: iter kt does QK(kt),
// PV(kt-1), exp(kt). P stays ENTIRELY in registers: V's key order is
// pre-permuted (norm_vt) so the QK output fragment IS the PV B-operand
// fragment -> sP deleted (LDS 73.7 -> 36.9 KB, 3 blocks/CU via
// __launch_bounds__(256,3)), 12 DS ops + P lgkm waits per iter deleted.
// l via ones-MFMA (permutation-invariant). 1-D grid, bid=qt*32+bh for XCD
// L2 locality. iq*ik*scale*log2(e) folded into Q frags -> exp2;
// cvt_pkrtz packs P; iv folded into epilogue.
// ---------------------------------------------------------------------------
#define LSTR 72

__global__ __launch_bounds__(256, 3) void attn_mfma(
    const _Float16* __restrict__ Qf, const _Float16* __restrict__ Kf,
    const _Float16* __restrict__ VT, const float* __restrict__ inv,
    _Float16* __restrict__ AO)
{
    const int bid = blockIdx.x;           // 512
    const int qt = bid >> 5;              // 16
    const int bh = bid & 31;              // 32 (bid%8 == bh%8 -> XCD locality)
    const int b = bh >> 3, h = bh & 7;
    const int tid = threadIdx.x;
    const int wave = tid >> 6, lane = tid & 63;
    const int quad = lane >> 4, lm = lane & 15;

    __shared__ _Float16 sK[2][64 * LSTR];
    __shared__ _Float16 sVT[2][64 * LSTR];

    // ---- Q fragments (B-operand: n=lm=query, k=quad*8+j)
    // iq*ik*0.125*log2(e) folded -> exp2 downstream.
    f16x8 qb[2][2];
    {
        const float* iqp = inv + b * Cc + h * 64;
        const float* ikp = inv + BC + b * Cc + h * 64;
#pragma unroll
        for (int qf = 0; qf < 2; ++qf) {
            const int row = qt * 128 + wave * 32 + qf * 16 + lm;
#pragma unroll
            for (int ks = 0; ks < 2; ++ks) {
                const int d0 = ks * 32 + quad * 8;
                f16x8 qv = *(const f16x8*)&Qf[(size_t)(b * Tt + row) * Cc + h * 64 + d0];
#pragma unroll
                for (int j = 0; j < 8; ++j) {
                    const float f = (float)qv[j] * iqp[d0 + j] * ikp[d0 + j] * 0.18033688011f;
                    qb[qf][ks][j] = (_Float16)f;
                }
            }
        }
    }

    f32x4 o[4][2];      // [cf][qf]: O^T frags, m=channel, n=query
#pragma unroll
    for (int cf = 0; cf < 4; ++cf)
#pragma unroll
        for (int qf = 0; qf < 2; ++qf) o[cf][qf] = (f32x4){0.f, 0.f, 0.f, 0.f};
    f32x4 ol[2];        // l accumulators via ones-MFMA (all elems = l[query])
#pragma unroll
    for (int qf = 0; qf < 2; ++qf) ol[qf] = (f32x4){0.f, 0.f, 0.f, 0.f};
    f16x8 ones;
#pragma unroll
    for (int j = 0; j < 8; ++j) ones[j] = (_Float16)1.0f;

    // P carried in registers between pipeline stages (compile-time indexed).
    f16x8 pb[2][2];
#pragma unroll
    for (int qf = 0; qf < 2; ++qf)
#pragma unroll
        for (int ks = 0; ks < 2; ++ks)
#pragma unroll
            for (int j = 0; j < 8; ++j) pb[qf][ks][j] = (_Float16)0.0f;

    const int sr0 = tid >> 3, sc0 = (tid & 7) * 8;
    const int sr1 = sr0 + 32;
    const _Float16* gK = Kf + (size_t)b * Tt * Cc + h * 64;
    const _Float16* gV = VT + ((size_t)b * Cc + h * 64) * Tt;

    f16x8 rk0, rk1, rv0, rv1;
    {
        rk0 = *(const f16x8*)&gK[(size_t)sr0 * Cc + sc0];
        rk1 = *(const f16x8*)&gK[(size_t)sr1 * Cc + sc0];
        rv0 = *(const f16x8*)&gV[(size_t)sr0 * Tt + sc0];
        rv1 = *(const f16x8*)&gV[(size_t)sr1 * Tt + sc0];
    }

    for (int kt = 0; kt < 32; ++kt) {
        const int cur = kt & 1, prv = cur ^ 1;
        _Float16* sKc = sK[cur];
        _Float16* sVc = sVT[cur];

        __syncthreads();
        *(f16x8*)&sKc[sr0 * LSTR + sc0] = rk0;
        *(f16x8*)&sKc[sr1 * LSTR + sc0] = rk1;
        *(f16x8*)&sVc[sr0 * LSTR + sc0] = rv0;
        *(f16x8*)&sVc[sr1 * LSTR + sc0] = rv1;
        __syncthreads();

        if (kt < 31) {
            const int t0 = (kt + 1) * 64;
            rk0 = *(const f16x8*)&gK[(size_t)(t0 + sr0) * Cc + sc0];
            rk1 = *(const f16x8*)&gK[(size_t)(t0 + sr1) * Cc + sc0];
            rv0 = *(const f16x8*)&gV[(size_t)sr0 * Tt + t0 + sc0];
            rv1 = *(const f16x8*)&gV[(size_t)sr1 * Tt + t0 + sc0];
        }

        // ---- S^T(kt) = K Q^T  (m=key, n=query)
        f32x4 st[4][2];
#pragma unroll
        for (int kf = 0; kf < 4; ++kf)
#pragma unroll
            for (int qf = 0; qf < 2; ++qf) st[kf][qf] = (f32x4){0.f, 0.f, 0.f, 0.f};
#pragma unroll
        for (int ks = 0; ks < 2; ++ks) {
            f16x8 ka[4];
#pragma unroll
            for (int kf = 0; kf < 4; ++kf)
                ka[kf] = *(const f16x8*)&sKc[(kf * 16 + lm) * LSTR + ks * 32 + quad * 8];
#pragma unroll
            for (int kf = 0; kf < 4; ++kf)
#pragma unroll
                for (int qf = 0; qf < 2; ++qf)
                    st[kf][qf] = __builtin_amdgcn_mfma_f32_16x16x32_f16(ka[kf], qb[qf][ks], st[kf][qf], 0, 0, 0);
        }

        // ---- PV(kt-1): O^T += VT P^T ; l += ones P^T  (pb = regs, V key-
        // order permuted to match, so no P shuffle/LDS needed)
        if (kt > 0) {
            _Float16* sVp = sVT[prv];
#pragma unroll
            for (int ks = 0; ks < 2; ++ks) {
                f16x8 va[4];
#pragma unroll
                for (int cf = 0; cf < 4; ++cf)
                    va[cf] = *(const f16x8*)&sVp[(cf * 16 + lm) * LSTR + ks * 32 + quad * 8];
#pragma unroll
                for (int cf = 0; cf < 4; ++cf)
#pragma unroll
                    for (int qf = 0; qf < 2; ++qf)
                        o[cf][qf] = __builtin_amdgcn_mfma_f32_16x16x32_f16(va[cf], pb[qf][ks], o[cf][qf], 0, 0, 0);
#pragma unroll
                for (int qf = 0; qf < 2; ++qf)
                    ol[qf] = __builtin_amdgcn_mfma_f32_16x16x32_f16(ones, pb[qf][ks], ol[qf], 0, 0, 0);
            }
        }

        // ---- p = exp2(s(kt)) -> pb regs. Slot j of pb[qf][ks]:
        // j=0..3 <- st[2ks][qf] (keys 2ks*16+q*4+r), j=4..7 <- st[2ks+1][qf].
#pragma unroll
        for (int ks = 0; ks < 2; ++ks)
#pragma unroll
            for (int qf = 0; qf < 2; ++qf) {
                const f32x4 a = st[2 * ks][qf];
                const f32x4 c = st[2 * ks + 1][qf];
                const f16x2 l0 = __builtin_bit_cast(f16x2, __builtin_amdgcn_cvt_pkrtz(
                    __builtin_amdgcn_exp2f(a[0]), __builtin_amdgcn_exp2f(a[1])));
                const f16x2 l1 = __builtin_bit_cast(f16x2, __builtin_amdgcn_cvt_pkrtz(
                    __builtin_amdgcn_exp2f(a[2]), __builtin_amdgcn_exp2f(a[3])));
                const f16x2 h0 = __builtin_bit_cast(f16x2, __builtin_amdgcn_cvt_pkrtz(
                    __builtin_amdgcn_exp2f(c[0]), __builtin_amdgcn_exp2f(c[1])));
                const f16x2 h1 = __builtin_bit_cast(f16x2, __builtin_amdgcn_cvt_pkrtz(
                    __builtin_amdgcn_exp2f(c[2]), __builtin_amdgcn_exp2f(c[3])));
                f16x8 p;
                p[0] = l0[0]; p[1] = l0[1]; p[2] = l1[0]; p[3] = l1[1];
                p[4] = h0[0]; p[5] = h0[1]; p[6] = h1[0]; p[7] = h1[1];
                pb[qf][ks] = p;
            }
    }

    // ---- drain PV(31): pb holds tile 31, V in sVT[1]
    {
        _Float16* sVp = sVT[1];
#pragma unroll
        for (int ks = 0; ks < 2; ++ks) {
            f16x8 va[4];
#pragma unroll
            for (int cf = 0; cf < 4; ++cf)
                va[cf] = *(const f16x8*)&sVp[(cf * 16 + lm) * LSTR + ks * 32 + quad * 8];
#pragma unroll
            for (int cf = 0; cf < 4; ++cf)
#pragma unroll
                for (int qf = 0; qf < 2; ++qf)
                    o[cf][qf] = __builtin_amdgcn_mfma_f32_16x16x32_f16(va[cf], pb[qf][ks], o[cf][qf], 0, 0, 0);
#pragma unroll
            for (int qf = 0; qf < 2; ++qf)
                ol[qf] = __builtin_amdgcn_mfma_f32_16x16x32_f16(ones, pb[qf][ks], ol[qf], 0, 0, 0);
        }
    }

    // ---- epilogue: il from ones-MFMA acc, O *= il * iv (per-channel), fp16
    float il[2];
#pragma unroll
    for (int qf = 0; qf < 2; ++qf) il[qf] = 1.0f / ol[qf][0];
    const float* ivp = inv + 2 * BC + b * Cc + h * 64;
    float iv[4][4];
#pragma unroll
    for (int cf = 0; cf < 4; ++cf) {
        float4 t = *(const float4*)&ivp[cf * 16 + quad * 4];
        iv[cf][0] = t.x; iv[cf][1] = t.y; iv[cf][2] = t.z; iv[cf][3] = t.w;
    }
#pragma unroll
    for (int qf = 0; qf < 2; ++qf) {
        const size_t row = (size_t)(b * Tt + qt * 128 + wave * 32 + qf * 16 + lm);
#pragma unroll
        for (int cf = 0; cf < 4; ++cf) {
            f16x4 pk;
#pragma unroll
            for (int r = 0; r < 4; ++r)
                pk[r] = (_Float16)(o[cf][qf][r] * il[qf] * iv[cf][r]);
            *(f16x4*)&AO[row * Cc + h * 64 + cf * 16 + quad * 4] = pk;
        }
    }
}

// ---------------------------------------------------------------------------
// Kernel 5: out = AO @ Wo + bo + residual, single-term fp16 MFMA.
// 64x128 tile, 4 waves (each 32x64).
// ---------------------------------------------------------------------------
__global__ __launch_bounds__(256, 2) void out_mfma(
    const _Float16* __restrict__ AO, const _Float16* __restrict__ Wt,
    const float* __restrict__ bo, const float* __restrict__ HS,
    float* __restrict__ Outp)
{
    const int mt = blockIdx.x;              // 128
    const int nt = blockIdx.y;              // 4
    const int tid = threadIdx.x;
    const int wave = tid >> 6, lane = tid & 63;
    const int quad = lane >> 4, lm = lane & 15;
    const int wm = (wave & 1) * 32, wn = (wave >> 1) * 64;

    __shared__ _Float16 sA[64 * 40];
    __shared__ _Float16 sB[128 * 40];

    f32x4 acc[2][4];
#pragma unroll
    for (int mf = 0; mf < 2; ++mf)
#pragma unroll
        for (int nf = 0; nf < 4; ++nf) acc[mf][nf] = (f32x4){0.f, 0.f, 0.f, 0.f};

    const int ra = tid >> 2, ka = (tid & 3) * 8;
    const int rb = tid >> 1, kb = (tid & 1) * 16;
    const _Float16* gah = AO + (size_t)(mt * 64 + ra) * Cc + ka;
    const _Float16* gbh = Wt + ((size_t)(3 * 512 + nt * 128 + rb)) * Cc + kb;

    for (int k0 = 0; k0 < Cc; k0 += 32) {
        __syncthreads();
        {
            *(f16x8*)&sA[ra * 40 + ka] = *(const f16x8*)&gah[k0];
            *(f16x8*)&sB[rb * 40 + kb]     = *(const f16x8*)&gbh[k0];
            *(f16x8*)&sB[rb * 40 + kb + 8] = *(const f16x8*)&gbh[k0 + 8];
        }
        __syncthreads();

        f16x8 ah[2], bh[4];
#pragma unroll
        for (int mf = 0; mf < 2; ++mf)
            ah[mf] = *(const f16x8*)&sA[(wm + mf * 16 + lm) * 40 + quad * 8];
#pragma unroll
        for (int nf = 0; nf < 4; ++nf)
            bh[nf] = *(const f16x8*)&sB[(wn + nf * 16 + lm) * 40 + quad * 8];
#pragma unroll
        for (int mf = 0; mf < 2; ++mf)
#pragma unroll
            for (int nf = 0; nf < 4; ++nf)
                acc[mf][nf] = __builtin_amdgcn_mfma_f32_16x16x32_f16(ah[mf], bh[nf], acc[mf][nf], 0, 0, 0);
    }

#pragma unroll
    for (int mf = 0; mf < 2; ++mf)
#pragma unroll
        for (int r = 0; r < 4; ++r) {
            const size_t m = (size_t)(mt * 64 + wm + mf * 16 + quad * 4 + r);
#pragma unroll
            for (int nf = 0; nf < 4; ++nf) {
                const int col = nt * 128 + wn + nf * 16 + lm;
                Outp[m * Cc + col] = acc[mf][nf][r] + bo[col] + HS[m * Cc + col];
            }
        }
}

// ---------------------------------------------------------------------------
extern "C" void kernel_launch(void* const* d_in, const int* in_sizes, int n_in,
                              void* d_out, int out_size, void* d_ws,
                              size_t ws_size, hipStream_t stream)
{
    const float* HS = (const float*)d_in[0];
    const float* Wq = (const float*)d_in[1];
    const float* Wk = (const float*)d_in[2];
    const float* Wv = (const float*)d_in[3];
    const float* Wo = (const float*)d_in[4];
    const float* bo = (const float*)d_in[5];
    float* out = (float*)d_out;

    const size_t SZ = (size_t)Bb * Tt * Cc;        // 4,194,304 elements
    _Float16* Qf  = (_Float16*)d_ws;
    _Float16* Kf  = Qf + SZ;
    _Float16* Vf  = Kf + SZ;
    _Float16* VTh = Vf + SZ;                        // also aliased as HSh
    _Float16* AO  = VTh + SZ;
    _Float16* Wt  = AO + SZ;                        // 4*Cc*Cc halves
    float* colsum = (float*)(Wt + 4 * Cc * Cc);
    float* inv    = colsum + 3 * BC;

    // HSh aliases the VTh region: hs_half -> qkv (reads) -> norm_vt
    // overwrites it with VT afterwards.
    _Float16* HSh = VTh;

    (void)hipMemsetAsync(colsum, 0, 3 * BC * sizeof(float), stream);

    wsetup<<<dim3(64, 4), 256, 0, stream>>>(Wq, Wk, Wv, Wo, Wt);

    hs_half<<<2048, 256, 0, stream>>>(HS, HSh);

    qkv_mfma<<<dim3(64, 4, 3), 256, 0, stream>>>(HSh, Wt, Qf, Kf, Vf, colsum);

    inv_norm_kernel<<<(3 * BC + 255) / 256, 256, 0, stream>>>(colsum, inv);

    norm_vt<<<1024, 256, 0, stream>>>(Vf, VTh);

    attn_mfma<<<dim3(512), 256, 0, stream>>>(Qf, Kf, VTh, inv, AO);

    out_mfma<<<dim3(128, 4), 256, 0, stream>>>(AO, Wt, bo, HS, out);
}

// Round 6
// 162.991 us; speedup vs baseline: 1.1829x; 1.0243x over previous
//
#include <hip/hip_runtime.h>

#define Tt 2048
#define Cc 512
#define Bb 4
#define BC (Bb * Cc)

typedef __attribute__((ext_vector_type(4))) float f32x4;
typedef __attribute__((ext_vector_type(8))) _Float16 f16x8;
typedef __attribute__((ext_vector_type(4))) _Float16 f16x4;
typedef __attribute__((ext_vector_type(2))) _Float16 f16x2;

// async global->LDS 16B copy: dest = wave-uniform LDS base + lane*16.
__device__ static inline void gl16(const _Float16* g, _Float16* l)
{
    __builtin_amdgcn_global_load_lds(
        (const __attribute__((address_space(1))) void*)g,
        (__attribute__((address_space(3))) void*)l, 16, 0, 0);
}

// ---------------------------------------------------------------------------
// Kernel 0: W[k][n] (x4) -> Wt[z][n][k] fp16 (single plane).
// ---------------------------------------------------------------------------
__global__ __launch_bounds__(256) void wsetup(
    const float* __restrict__ Wq, const float* __restrict__ Wk,
    const float* __restrict__ Wv, const float* __restrict__ Wo,
    _Float16* __restrict__ Wt)
{
    const int z = blockIdx.y;
    const float* W = (z == 0) ? Wq : (z == 1) ? Wk : (z == 2) ? Wv : Wo;
    const int k0 = (blockIdx.x >> 3) * 64, n0 = (blockIdx.x & 7) * 64;
    const int tid = threadIdx.x;
    __shared__ float tile[64][65];

#pragma unroll
    for (int i = 0; i < 4; ++i) {
        const int idx = i * 256 + tid;
        const int kr = idx >> 4, c4 = idx & 15;
        float4 v = *(const float4*)&W[(size_t)(k0 + kr) * Cc + n0 + c4 * 4];
        tile[kr][c4 * 4 + 0] = v.x; tile[kr][c4 * 4 + 1] = v.y;
        tile[kr][c4 * 4 + 2] = v.z; tile[kr][c4 * 4 + 3] = v.w;
    }
    __syncthreads();
#pragma unroll
    for (int i = 0; i < 4; ++i) {
        const int idx = i * 256 + tid;
        const int nr = idx >> 4, k4 = idx & 15;
        f16x4 o;
        o[0] = (_Float16)tile[k4 * 4 + 0][nr];
        o[1] = (_Float16)tile[k4 * 4 + 1][nr];
        o[2] = (_Float16)tile[k4 * 4 + 2][nr];
        o[3] = (_Float16)tile[k4 * 4 + 3][nr];
        *(f16x4*)&Wt[((size_t)(z * 512 + n0 + nr)) * Cc + k0 + k4 * 4] = o;
    }
}

// ---------------------------------------------------------------------------
// Kernel 0b: HS fp32 -> fp16 (one shot).
// ---------------------------------------------------------------------------
__global__ __launch_bounds__(256) void hs_half(
    const float* __restrict__ HS, _Float16* __restrict__ HSh)
{
    const size_t i = ((size_t)blockIdx.x * 256 + threadIdx.x) * 8;
    float4 a = *(const float4*)&HS[i];
    float4 b = *(const float4*)&HS[i + 4];
    f16x8 o;
    o[0] = (_Float16)a.x; o[1] = (_Float16)a.y;
    o[2] = (_Float16)a.z; o[3] = (_Float16)a.w;
    o[4] = (_Float16)b.x; o[5] = (_Float16)b.y;
    o[6] = (_Float16)b.z; o[7] = (_Float16)b.w;
    *(f16x8*)&HSh[i] = o;
}

// ---------------------------------------------------------------------------
// Kernel 1: QKV GEMM, fp16 MFMA, 128x128 tile, 4 waves, BK=32.
// Staging via global_load_lds (async, no VGPR round-trip): linear [128][32]
// LDS slabs, 2 A + 2 B calls per wave per iter (m97/T-catalog structure).
// Epilogue: fp16 store + per-(b,channel) column sum-of-squares.
// ---------------------------------------------------------------------------
__global__ __launch_bounds__(256, 3) void qkv_mfma(
    const _Float16* __restrict__ HSh, const _Float16* __restrict__ Wt,
    _Float16* __restrict__ Qf, _Float16* __restrict__ Kf,
    _Float16* __restrict__ Vf, float* __restrict__ colsum)
{
    const int mt = blockIdx.x;              // 64
    const int nt = blockIdx.y;              // 4
    const int z  = blockIdx.z;              // 3
    _Float16* Out = (z == 0) ? Qf : (z == 1) ? Kf : Vf;

    const int tid = threadIdx.x;
    const int wave = tid >> 6, lane = tid & 63;
    const int quad = lane >> 4, lm = lane & 15;
    const int wm = (wave & 1) * 64, wn = (wave >> 1) * 64;

    __shared__ _Float16 sA[128 * 32];       // 8 KB, [row][32 halves] linear
    __shared__ _Float16 sB[128 * 32];       // 8 KB

    f32x4 acc[4][4];
#pragma unroll
    for (int mf = 0; mf < 4; ++mf)
#pragma unroll
        for (int nf = 0; nf < 4; ++nf) acc[mf][nf] = (f32x4){0.f, 0.f, 0.f, 0.f};

    const int lr = lane >> 2;               // 0..15 row within 16-row call
    const int lc = (lane & 3) * 8;          // half col within BK=32
    const _Float16* gaA = HSh + (size_t)(mt * 128 + wave * 32 + lr) * Cc + lc;
    const _Float16* gaB = Wt + ((size_t)(z * 512 + nt * 128 + wave * 32 + lr)) * Cc + lc;
    _Float16* ldA = &sA[wave * 1024];       // wave's 32 rows
    _Float16* ldB = &sB[wave * 1024];

    for (int k0 = 0; k0 < Cc; k0 += 32) {
        __syncthreads();
        gl16(gaA + k0,            ldA);
        gl16(gaA + 16 * Cc + k0,  ldA + 512);
        gl16(gaB + k0,            ldB);
        gl16(gaB + 16 * Cc + k0,  ldB + 512);
        __syncthreads();

        f16x8 ah[4], bh[4];
#pragma unroll
        for (int mf = 0; mf < 4; ++mf)
            ah[mf] = *(const f16x8*)&sA[(wm + mf * 16 + lm) * 32 + quad * 8];
#pragma unroll
        for (int nf = 0; nf < 4; ++nf)
            bh[nf] = *(const f16x8*)&sB[(wn + nf * 16 + lm) * 32 + quad * 8];
#pragma unroll
        for (int mf = 0; mf < 4; ++mf)
#pragma unroll
            for (int nf = 0; nf < 4; ++nf)
                acc[mf][nf] = __builtin_amdgcn_mfma_f32_16x16x32_f16(ah[mf], bh[nf], acc[mf][nf], 0, 0, 0);
    }

    const int bidx = mt >> 4;
#pragma unroll
    for (int nf = 0; nf < 4; ++nf) {
        float cs = 0.f;
#pragma unroll
        for (int mf = 0; mf < 4; ++mf)
#pragma unroll
            for (int r = 0; r < 4; ++r) {
                const float v = acc[mf][nf][r];
                const size_t idx =
                    (size_t)(mt * 128 + wm + mf * 16 + quad * 4 + r) * Cc +
                    nt * 128 + wn + nf * 16 + lm;
                Out[idx] = (_Float16)v;
                cs += v * v;
            }
        cs += __shfl_xor(cs, 16, 64);
        cs += __shfl_xor(cs, 32, 64);
        if (lane < 16)
            atomicAdd(&colsum[(size_t)z * BC + bidx * Cc + nt * 128 + wn + nf * 16 + lane], cs);
    }
}

// ---------------------------------------------------------------------------
// Kernel 2: colsum -> 1/sqrt(mean + eps)
// ---------------------------------------------------------------------------
__global__ void inv_norm_kernel(const float* __restrict__ colsum,
                                float* __restrict__ inv)
{
    const int i = blockIdx.x * blockDim.x + threadIdx.x;
    if (i < 3 * BC) inv[i] = rsqrtf(colsum[i] * (1.0f / Tt) + 1e-4f);
}

// ---------------------------------------------------------------------------
// Kernel 3: V[b][t][c] fp16 -> VT[b][c][t'] fp16, key-permuted within each
// 64-block: t = b5*32 + u*16 + q*4 + r -> t' = b5*32 + q*8 + u*4 + r.
// ---------------------------------------------------------------------------
__global__ __launch_bounds__(256) void norm_vt(
    const _Float16* __restrict__ V, _Float16* __restrict__ VT)
{
    const int blk = blockIdx.x;          // 4 * 8 * 32 = 1024
    const int b = blk >> 8, ct = (blk >> 5) & 7, tt = blk & 31;
    const int t0 = tt * 64, c0 = ct * 64;
    const int tid = threadIdx.x;

    __shared__ _Float16 tile[64 * 72];

#pragma unroll
    for (int i = 0; i < 2; ++i) {
        const int idx = i * 256 + tid;
        const int tr = idx >> 3, c8 = (idx & 7) * 8;
        *(f16x8*)&tile[tr * 72 + c8] =
            *(const f16x8*)&V[(size_t)(b * Tt + t0 + tr) * Cc + c0 + c8];
    }
    __syncthreads();
#pragma unroll
    for (int i = 0; i < 2; ++i) {
        const int idx = i * 256 + tid;
        const int cr = idx >> 3, u = idx & 7;   // u = keys [u*8, u*8+7]
        const int C0 = ((u >> 2) & 1) * 32 + (u & 1) * 16 + ((u >> 1) & 1) * 4;
        f16x4 oa, ob;
#pragma unroll
        for (int j = 0; j < 4; ++j) oa[j] = tile[(u * 8 + j) * 72 + cr];
#pragma unroll
        for (int j = 0; j < 4; ++j) ob[j] = tile[(u * 8 + 4 + j) * 72 + cr];
        _Float16* dst = &VT[(size_t)(b * Cc + c0 + cr) * Tt + t0];
        *(f16x4*)&dst[C0]     = oa;
        *(f16x4*)&dst[C0 + 8] = ob;
    }
}

// ---------------------------------------------------------------------------
// Kernel 4: fp16 MFMA flash attention, transposed (S^T / O^T) form.
// 4 waves, 32 queries/wave, cross-iteration pipeline (QK(kt) | PV(kt-1) |
// exp(kt)), P in registers via pre-permuted V. setprio(1) around MFMA
// clusters (T5); kt loop unrolled x2 for static buffer indexing.
// ---------------------------------------------------------------------------
#define LSTR 72

__global__ __launch_bounds__(256, 3) void attn_mfma(
    const _Float16* __restrict__ Qf, const _Float16* __restrict__ Kf,
    const _Float16* __restrict__ VT, const float* __restrict__ inv,
    _Float16* __restrict__ AO)
{
    const int bid = blockIdx.x;           // 512
    const int qt = bid >> 5;              // 16
    const int bh = bid & 31;              // 32 (bid%8 == bh%8 -> XCD locality)
    const int b = bh >> 3, h = bh & 7;
    const int tid = threadIdx.x;
    const int wave = tid >> 6, lane = tid & 63;
    const int quad = lane >> 4, lm = lane & 15;

    __shared__ _Float16 sK[2][64 * LSTR];
    __shared__ _Float16 sVT[2][64 * LSTR];

    f16x8 qb[2][2];
    {
        const float* iqp = inv + b * Cc + h * 64;
        const float* ikp = inv + BC + b * Cc + h * 64;
#pragma unroll
        for (int qf = 0; qf < 2; ++qf) {
            const int row = qt * 128 + wave * 32 + qf * 16 + lm;
#pragma unroll
            for (int ks = 0; ks < 2; ++ks) {
                const int d0 = ks * 32 + quad * 8;
                f16x8 qv = *(const f16x8*)&Qf[(size_t)(b * Tt + row) * Cc + h * 64 + d0];
#pragma unroll
                for (int j = 0; j < 8; ++j) {
                    const float f = (float)qv[j] * iqp[d0 + j] * ikp[d0 + j] * 0.18033688011f;
                    qb[qf][ks][j] = (_Float16)f;
                }
            }
        }
    }

    f32x4 o[4][2];
#pragma unroll
    for (int cf = 0; cf < 4; ++cf)
#pragma unroll
        for (int qf = 0; qf < 2; ++qf) o[cf][qf] = (f32x4){0.f, 0.f, 0.f, 0.f};
    f32x4 ol[2];
#pragma unroll
    for (int qf = 0; qf < 2; ++qf) ol[qf] = (f32x4){0.f, 0.f, 0.f, 0.f};
    f16x8 ones;
#pragma unroll
    for (int j = 0; j < 8; ++j) ones[j] = (_Float16)1.0f;

    f16x8 pb[2][2];
#pragma unroll
    for (int qf = 0; qf < 2; ++qf)
#pragma unroll
        for (int ks = 0; ks < 2; ++ks)
#pragma unroll
            for (int j = 0; j < 8; ++j) pb[qf][ks][j] = (_Float16)0.0f;

    const int sr0 = tid >> 3, sc0 = (tid & 7) * 8;
    const int sr1 = sr0 + 32;
    const _Float16* gK = Kf + (size_t)b * Tt * Cc + h * 64;
    const _Float16* gV = VT + ((size_t)b * Cc + h * 64) * Tt;

    f16x8 rk0, rk1, rv0, rv1;
    {
        rk0 = *(const f16x8*)&gK[(size_t)sr0 * Cc + sc0];
        rk1 = *(const f16x8*)&gK[(size_t)sr1 * Cc + sc0];
        rv0 = *(const f16x8*)&gV[(size_t)sr0 * Tt + sc0];
        rv1 = *(const f16x8*)&gV[(size_t)sr1 * Tt + sc0];
    }

#pragma unroll 2
    for (int kt = 0; kt < 32; ++kt) {
        const int cur = kt & 1, prv = cur ^ 1;
        _Float16* sKc = sK[cur];
        _Float16* sVc = sVT[cur];

        __syncthreads();
        *(f16x8*)&sKc[sr0 * LSTR + sc0] = rk0;
        *(f16x8*)&sKc[sr1 * LSTR + sc0] = rk1;
        *(f16x8*)&sVc[sr0 * LSTR + sc0] = rv0;
        *(f16x8*)&sVc[sr1 * LSTR + sc0] = rv1;
        __syncthreads();

        if (kt < 31) {
            const int t0 = (kt + 1) * 64;
            rk0 = *(const f16x8*)&gK[(size_t)(t0 + sr0) * Cc + sc0];
            rk1 = *(const f16x8*)&gK[(size_t)(t0 + sr1) * Cc + sc0];
            rv0 = *(const f16x8*)&gV[(size_t)sr0 * Tt + t0 + sc0];
            rv1 = *(const f16x8*)&gV[(size_t)sr1 * Tt + t0 + sc0];
        }

        // ---- S^T(kt) = K Q^T
        f32x4 st[4][2];
#pragma unroll
        for (int kf = 0; kf < 4; ++kf)
#pragma unroll
            for (int qf = 0; qf < 2; ++qf) st[kf][qf] = (f32x4){0.f, 0.f, 0.f, 0.f};
#pragma unroll
        for (int ks = 0; ks < 2; ++ks) {
            f16x8 ka[4];
#pragma unroll
            for (int kf = 0; kf < 4; ++kf)
                ka[kf] = *(const f16x8*)&sKc[(kf * 16 + lm) * LSTR + ks * 32 + quad * 8];
            __builtin_amdgcn_s_setprio(1);
#pragma unroll
            for (int kf = 0; kf < 4; ++kf)
#pragma unroll
                for (int qf = 0; qf < 2; ++qf)
                    st[kf][qf] = __builtin_amdgcn_mfma_f32_16x16x32_f16(ka[kf], qb[qf][ks], st[kf][qf], 0, 0, 0);
            __builtin_amdgcn_s_setprio(0);
        }

        // ---- PV(kt-1): O^T += VT P^T ; l += ones P^T
        if (kt > 0) {
            _Float16* sVp = sVT[prv];
#pragma unroll
            for (int ks = 0; ks < 2; ++ks) {
                f16x8 va[4];
#pragma unroll
                for (int cf = 0; cf < 4; ++cf)
                    va[cf] = *(const f16x8*)&sVp[(cf * 16 + lm) * LSTR + ks * 32 + quad * 8];
                __builtin_amdgcn_s_setprio(1);
#pragma unroll
                for (int cf = 0; cf < 4; ++cf)
#pragma unroll
                    for (int qf = 0; qf < 2; ++qf)
                        o[cf][qf] = __builtin_amdgcn_mfma_f32_16x16x32_f16(va[cf], pb[qf][ks], o[cf][qf], 0, 0, 0);
#pragma unroll
                for (int qf = 0; qf < 2; ++qf)
                    ol[qf] = __builtin_amdgcn_mfma_f32_16x16x32_f16(ones, pb[qf][ks], ol[qf], 0, 0, 0);
                __builtin_amdgcn_s_setprio(0);
            }
        }

        // ---- p = exp2(s(kt)) -> pb regs
#pragma unroll
        for (int ks = 0; ks < 2; ++ks)
#pragma unroll
            for (int qf = 0; qf < 2; ++qf) {
                const f32x4 a = st[2 * ks][qf];
                const f32x4 c = st[2 * ks + 1][qf];
                const f16x2 l0 = __builtin_bit_cast(f16x2, __builtin_amdgcn_cvt_pkrtz(
                    __builtin_amdgcn_exp2f(a[0]), __builtin_amdgcn_exp2f(a[1])));
                const f16x2 l1 = __builtin_bit_cast(f16x2, __builtin_amdgcn_cvt_pkrtz(
                    __builtin_amdgcn_exp2f(a[2]), __builtin_amdgcn_exp2f(a[3])));
                const f16x2 h0 = __builtin_bit_cast(f16x2, __builtin_amdgcn_cvt_pkrtz(
                    __builtin_amdgcn_exp2f(c[0]), __builtin_amdgcn_exp2f(c[1])));
                const f16x2 h1 = __builtin_bit_cast(f16x2, __builtin_amdgcn_cvt_pkrtz(
                    __builtin_amdgcn_exp2f(c[2]), __builtin_amdgcn_exp2f(c[3])));
                f16x8 p;
                p[0] = l0[0]; p[1] = l0[1]; p[2] = l1[0]; p[3] = l1[1];
                p[4] = h0[0]; p[5] = h0[1]; p[6] = h1[0]; p[7] = h1[1];
                pb[qf][ks] = p;
            }
    }

    // ---- drain PV(31)
    {
        _Float16* sVp = sVT[1];
#pragma unroll
        for (int ks = 0; ks < 2; ++ks) {
            f16x8 va[4];
#pragma unroll
            for (int cf = 0; cf < 4; ++cf)
                va[cf] = *(const f16x8*)&sVp[(cf * 16 + lm) * LSTR + ks * 32 + quad * 8];
#pragma unroll
            for (int cf = 0; cf < 4; ++cf)
#pragma unroll
                for (int qf = 0; qf < 2; ++qf)
                    o[cf][qf] = __builtin_amdgcn_mfma_f32_16x16x32_f16(va[cf], pb[qf][ks], o[cf][qf], 0, 0, 0);
#pragma unroll
            for (int qf = 0; qf < 2; ++qf)
                ol[qf] = __builtin_amdgcn_mfma_f32_16x16x32_f16(ones, pb[qf][ks], ol[qf], 0, 0, 0);
        }
    }

    // ---- epilogue
    float il[2];
#pragma unroll
    for (int qf = 0; qf < 2; ++qf) il[qf] = 1.0f / ol[qf][0];
    const float* ivp = inv + 2 * BC + b * Cc + h * 64;
    float iv[4][4];
#pragma unroll
    for (int cf = 0; cf < 4; ++cf) {
        float4 t = *(const float4*)&ivp[cf * 16 + quad * 4];
        iv[cf][0] = t.x; iv[cf][1] = t.y; iv[cf][2] = t.z; iv[cf][3] = t.w;
    }
#pragma unroll
    for (int qf = 0; qf < 2; ++qf) {
        const size_t row = (size_t)(b * Tt + qt * 128 + wave * 32 + qf * 16 + lm);
#pragma unroll
        for (int cf = 0; cf < 4; ++cf) {
            f16x4 pk;
#pragma unroll
            for (int r = 0; r < 4; ++r)
                pk[r] = (_Float16)(o[cf][qf][r] * il[qf] * iv[cf][r]);
            *(f16x4*)&AO[row * Cc + h * 64 + cf * 16 + quad * 4] = pk;
        }
    }
}

// ---------------------------------------------------------------------------
// Kernel 5: out = AO @ Wo + bo + residual. 64x128 tile, 4 waves, BK=32,
// global_load_lds staging (linear [64][32] / [128][32] slabs).
// ---------------------------------------------------------------------------
__global__ __launch_bounds__(256, 2) void out_mfma(
    const _Float16* __restrict__ AO, const _Float16* __restrict__ Wt,
    const float* __restrict__ bo, const float* __restrict__ HS,
    float* __restrict__ Outp)
{
    const int mt = blockIdx.x;              // 128
    const int nt = blockIdx.y;              // 4
    const int tid = threadIdx.x;
    const int wave = tid >> 6, lane = tid & 63;
    const int quad = lane >> 4, lm = lane & 15;
    const int wm = (wave & 1) * 32, wn = (wave >> 1) * 64;

    __shared__ _Float16 sA[64 * 32];        // 4 KB
    __shared__ _Float16 sB[128 * 32];       // 8 KB

    f32x4 acc[2][4];
#pragma unroll
    for (int mf = 0; mf < 2; ++mf)
#pragma unroll
        for (int nf = 0; nf < 4; ++nf) acc[mf][nf] = (f32x4){0.f, 0.f, 0.f, 0.f};

    const int lr = lane >> 2;               // 0..15
    const int lc = (lane & 3) * 8;
    const _Float16* gaA = AO + (size_t)(mt * 64 + wave * 16 + lr) * Cc + lc;
    const _Float16* gaB = Wt + ((size_t)(3 * 512 + nt * 128 + wave * 32 + lr)) * Cc + lc;
    _Float16* ldA = &sA[wave * 512];
    _Float16* ldB = &sB[wave * 1024];

    for (int k0 = 0; k0 < Cc; k0 += 32) {
        __syncthreads();
        gl16(gaA + k0,           ldA);
        gl16(gaB + k0,           ldB);
        gl16(gaB + 16 * Cc + k0, ldB + 512);
        __syncthreads();

        f16x8 ah[2], bh[4];
#pragma unroll
        for (int mf = 0; mf < 2; ++mf)
            ah[mf] = *(const f16x8*)&sA[(wm + mf * 16 + lm) * 32 + quad * 8];
#pragma unroll
        for (int nf = 0; nf < 4; ++nf)
            bh[nf] = *(const f16x8*)&sB[(wn + nf * 16 + lm) * 32 + quad * 8];
#pragma unroll
        for (int mf = 0; mf < 2; ++mf)
#pragma unroll
            for (int nf = 0; nf < 4; ++nf)
                acc[mf][nf] = __builtin_amdgcn_mfma_f32_16x16x32_f16(ah[mf], bh[nf], acc[mf][nf], 0, 0, 0);
    }

#pragma unroll
    for (int mf = 0; mf < 2; ++mf)
#pragma unroll
        for (int r = 0; r < 4; ++r) {
            const size_t m = (size_t)(mt * 64 + wm + mf * 16 + quad * 4 + r);
#pragma unroll
            for (int nf = 0; nf < 4; ++nf) {
                const int col = nt * 128 + wn + nf * 16 + lm;
                Outp[m * Cc + col] = acc[mf][nf][r] + bo[col] + HS[m * Cc + col];
            }
        }
}

// ---------------------------------------------------------------------------
extern "C" void kernel_launch(void* const* d_in, const int* in_sizes, int n_in,
                              void* d_out, int out_size, void* d_ws,
                              size_t ws_size, hipStream_t stream)
{
    const float* HS = (const float*)d_in[0];
    const float* Wq = (const float*)d_in[1];
    const float* Wk = (const float*)d_in[2];
    const float* Wv = (const float*)d_in[3];
    const float* Wo = (const float*)d_in[4];
    const float* bo = (const float*)d_in[5];
    float* out = (float*)d_out;

    const size_t SZ = (size_t)Bb * Tt * Cc;        // 4,194,304 elements
    _Float16* Qf  = (_Float16*)d_ws;
    _Float16* Kf  = Qf + SZ;
    _Float16* Vf  = Kf + SZ;
    _Float16* VTh = Vf + SZ;                        // also aliased as HSh
    _Float16* AO  = VTh + SZ;
    _Float16* Wt  = AO + SZ;                        // 4*Cc*Cc halves
    float* colsum = (float*)(Wt + 4 * Cc * Cc);
    float* inv    = colsum + 3 * BC;

    _Float16* HSh = VTh;

    (void)hipMemsetAsync(colsum, 0, 3 * BC * sizeof(float), stream);

    wsetup<<<dim3(64, 4), 256, 0, stream>>>(Wq, Wk, Wv, Wo, Wt);

    hs_half<<<2048, 256, 0, stream>>>(HS, HSh);

    qkv_mfma<<<dim3(64, 4, 3), 256, 0, stream>>>(HSh, Wt, Qf, Kf, Vf, colsum);

    inv_norm_kernel<<<(3 * BC + 255) / 256, 256, 0, stream>>>(colsum, inv);

    norm_vt<<<1024, 256, 0, stream>>>(Vf, VTh);

    attn_mfma<<<dim3(512), 256, 0, stream>>>(Qf, Kf, VTh, inv, AO);

    out_mfma<<<dim3(128, 4), 256, 0, stream>>>(AO, Wt, bo, HS, out);
}